// Round 6
// baseline (593.407 us; speedup 1.0000x reference)
//
#include <hip/hip_runtime.h>
#include <math.h>

#define NB 32
#define NS 8192
#define NC 64
#define NM 16
#define NL 4
#define NM2 32                 // 2*M (cos,sin interleaved)
#define NSBF 32                // forward-DFT superblocks per batch
#define PAD 65                 // LDS row pad (floats) for conflict-free reads

typedef float f16v __attribute__((ext_vector_type(16)));

static __device__ __forceinline__ f16v zero16() {
    f16v v;
    #pragma unroll
    for (int j = 0; j < 16; ++j) v[j] = 0.0f;
    return v;
}

static __device__ __forceinline__ float gelu_exact(float v) {
    return 0.5f * v * (1.0f + erff(v * 0.7071067811865475f));
}

// Build trig table T[s][2m]=cos(2*pi*m*s/NS), T[s][2m+1]=sin(2*pi*m*s/NS)
__global__ void k_table(float* __restrict__ T) {
    int s = blockIdx.x * blockDim.x + threadIdx.x;
    if (s >= NS) return;
    const float w = 6.283185307179586f / (float)NS;
    float* row = T + (size_t)s * NM2;
    #pragma unroll
    for (int m = 0; m < NM; ++m) {
        int idx = (m * s) & (NS - 1);
        float a = w * (float)idx;
        float sv, cv;
        sincosf(a, &sv, &cv);
        row[2*m]   = cv;
        row[2*m+1] = sv;
    }
}

// Transpose Wl_w [L][o][i] -> Wt [L][i][o]; d1_w [o][i] -> d1t [i][o]
__global__ void k_prep(const float* __restrict__ Ww, const float* __restrict__ d1w,
                       float* __restrict__ Wt, float* __restrict__ d1t) {
    int idx = blockIdx.x * 256 + threadIdx.x;
    if (idx < NL*NC*NC) {
        int l = idx / (NC*NC), r = idx % (NC*NC);
        int i = r / NC, o = r % NC;
        Wt[idx] = Ww[(size_t)l*NC*NC + (size_t)o*NC + i];
    } else if (idx < NL*NC*NC + NC*NC) {
        int r = idx - NL*NC*NC;
        int i = r / NC, o = r % NC;
        d1t[r] = d1w[(size_t)o*NC + i];
    }
}

// h[b,s,c] = input[b,s,0]*enc_w[c] + enc_b[c]
__global__ void __launch_bounds__(256) k_enc(const float* __restrict__ x,
                                             const float* __restrict__ ew,
                                             const float* __restrict__ eb,
                                             float* __restrict__ h) {
    int p = blockIdx.x * blockDim.x + threadIdx.x;   // 0..NB*NS-1
    float xv = x[p];
    float4* out = (float4*)(h + (size_t)p * NC);
    #pragma unroll
    for (int q = 0; q < NC/4; ++q) {
        float4 w4 = ((const float4*)ew)[q];
        float4 b4 = ((const float4*)eb)[q];
        out[q] = make_float4(fmaf(xv, w4.x, b4.x), fmaf(xv, w4.y, b4.y),
                             fmaf(xv, w4.z, b4.z), fmaf(xv, w4.w, b4.w));
    }
}

// Forward partial DFT. Wave = 64 channel lanes sharing one position at a time;
// trig row is wave-uniform (s_load). Accumulators are ext_vector values.
// LDS reduce buffer padded to 33 floats/row (conflict-free writes).
__global__ void __launch_bounds__(256) k_fwd(const float* __restrict__ h,
                                             const float* __restrict__ T,
                                             float* __restrict__ partial) {
    __shared__ float red[4 * NC * 33];    // 33.8 KB
    int b = blockIdx.y, sb = blockIdx.x;
    int t = threadIdx.x;
    int w = t >> 6, lane = t & 63;        // lane = channel c
    const int PPW = NS / NSBF / 4;        // 64 positions per wave
    f16v A0 = zero16(), A1 = zero16();
    int s0 = sb * (NS / NSBF) + w * PPW;
    const float* hp = h + ((size_t)b*NS + s0)*NC + lane;
    #pragma unroll 2
    for (int it = 0; it < PPW; ++it) {
        float hv = hp[(size_t)it * NC];
        int su = __builtin_amdgcn_readfirstlane(s0 + it);
        const f16v* tr = (const f16v*)(T + (size_t)su * NM2);
        A0 += hv * tr[0];
        A1 += hv * tr[1];
    }
    float* rr = &red[(w*NC + lane) * 33];
    #pragma unroll
    for (int j = 0; j < 16; ++j) rr[j] = A0[j];
    #pragma unroll
    for (int j = 0; j < 16; ++j) rr[16 + j] = A1[j];
    __syncthreads();
    float* pout = partial + ((size_t)b*NSBF + sb) * (NC*NM2);
    #pragma unroll
    for (int e = 0; e < (NC*NM2)/256; ++e) {
        int idx = t + 256*e;              // idx = c*32 + k
        int c = idx >> 5, k = idx & 31;
        pout[idx] = red[c*33 + k] + red[(NC + c)*33 + k]
                  + red[(2*NC + c)*33 + k] + red[(3*NC + c)*33 + k];
    }
}

// Reduce partials -> x_ft, apply complex R mixing, pre-scale for inverse.
// Writes TRANSPOSED yst[b][k][o] so k_spec reads o-contiguous (uniform s_loads).
__global__ void __launch_bounds__(256) k_mix(const float* __restrict__ partial,
                                             const float* __restrict__ Rre,
                                             const float* __restrict__ Rim,
                                             float* __restrict__ yst, int l) {
    __shared__ float xf[NC*NM2];   // 8 KB
    int b = blockIdx.x, t = threadIdx.x;
    #pragma unroll
    for (int e = 0; e < (NC*NM2)/256; ++e) {
        int idx = t + 256*e;
        float s = 0.f;
        #pragma unroll 8
        for (int sb = 0; sb < NSBF; ++sb)
            s += partial[((size_t)b*NSBF + sb)*(NC*NM2) + idx];
        xf[idx] = s;
    }
    __syncthreads();
    #pragma unroll
    for (int j = 0; j < (NC*NM)/256; ++j) {    // 4 (o,m) pairs/thread
        int p = t + 256*j;
        int o = p >> 4, m = p & 15;
        float yre = 0.f, yim = 0.f;
        #pragma unroll 8
        for (int i = 0; i < NC; ++i) {
            float xr = xf[i*NM2 + 2*m];
            float xs = xf[i*NM2 + 2*m + 1];
            size_t ridx = (((size_t)l*NC + i)*NC + o)*NM + m;
            float rr = Rre[ridx], ri = Rim[ridx];
            yre = fmaf(xr, rr, yre); yre = fmaf(xs, ri, yre);
            yim = fmaf(xr, ri, yim); yim = fmaf(-xs, rr, yim);
        }
        float* yb = yst + (size_t)b*NM2*NC;
        if (m == 0) { yb[o] = yre * (1.0f/NS); yb[NC + o] = 0.f; }
        else {
            yb[(size_t)(2*m)*NC + o]   = yre * (2.0f/NS);
            yb[(size_t)(2*m+1)*NC + o] = -yim * (2.0f/NS);
        }
    }
}

// Fused spectral + Wl + GELU, in-place on h. Block = 256 consecutive positions.
// h-tile staged coalesced -> LDS (padded rows); trig generated in-register
// (1 sincosf + 15 rotations) overlapping the staging loads; dense loop reads
// h from LDS; weights/ys rows are wave-uniform s_loads.
__global__ void __launch_bounds__(256) k_spec(float* __restrict__ h,
                                              const float* __restrict__ yst,
                                              const float* __restrict__ Wt,
                                              const float* __restrict__ Wb,
                                              int l) {
    __shared__ float hs[256 * PAD];   // 66.56 KB
    int b = blockIdx.y;
    int t = threadIdx.x;
    int s0 = blockIdx.x * 256;
    int s = s0 + t;
    const float4* hblk = (const float4*)(h + ((size_t)b*NS + s0)*NC);

    // 1) issue coalesced tile loads (latency overlapped with spectral below)
    float4 ld[16];
    #pragma unroll
    for (int j = 0; j < 16; ++j) ld[j] = hblk[t + 256*j];

    const float* Wl = Wt + (size_t)l*NC*NC;    // [i][o]
    const float* bl = Wb + (size_t)l*NC;
    const float* yb = yst + (size_t)b*NM2*NC;  // [k][o]

    f16v a0 = ((const f16v*)bl)[0];
    f16v a1 = ((const f16v*)bl)[1];
    f16v a2 = ((const f16v*)bl)[2];
    f16v a3 = ((const f16v*)bl)[3];

    // 2) spectral: a[o] += sum_m cos(m th)*yc_m[o] + sin(m th)*ys_m[o]
    {
        const f16v* y0 = (const f16v*)yb;      // m=0 cos row (sin row is zero)
        a0 += y0[0]; a1 += y0[1]; a2 += y0[2]; a3 += y0[3];
        float ang = (float)s * (6.283185307179586f / (float)NS);
        float c1, s1;
        sincosf(ang, &s1, &c1);
        float cm = c1, sm = s1;
        #pragma unroll 1
        for (int m = 1; m < NM; ++m) {
            const f16v* yc = (const f16v*)(yb + (size_t)(2*m)*NC);
            const f16v* ys = (const f16v*)(yb + (size_t)(2*m+1)*NC);
            a0 += cm * yc[0]; a1 += cm * yc[1]; a2 += cm * yc[2]; a3 += cm * yc[3];
            a0 += sm * ys[0]; a1 += sm * ys[1]; a2 += sm * ys[2]; a3 += sm * ys[3];
            float cn = cm*c1 - sm*s1;
            sm = cm*s1 + sm*c1;
            cm = cn;
        }
    }

    // 3) stage tile into LDS (transpose to padded per-position rows)
    #pragma unroll
    for (int j = 0; j < 16; ++j) {
        int idx = t + 256*j;              // linear float4 index in tile
        int ss = idx >> 4, q = idx & 15;
        float* d = &hs[ss*PAD + 4*q];
        d[0] = ld[j].x; d[1] = ld[j].y; d[2] = ld[j].z; d[3] = ld[j].w;
    }
    __syncthreads();

    // 4) dense: a[o] += sum_i h[i] * Wt[i][o]   (h from LDS, conflict-free)
    const float* hrow = &hs[t * PAD];
    #pragma unroll 1
    for (int i = 0; i < NC; i += 4) {
        float h0 = hrow[i], h1 = hrow[i+1], h2 = hrow[i+2], h3 = hrow[i+3];
        const f16v* w = (const f16v*)(Wl + (size_t)i*NC);
        a0 += h0 * w[0];  a1 += h0 * w[1];  a2 += h0 * w[2];  a3 += h0 * w[3];
        a0 += h1 * w[4];  a1 += h1 * w[5];  a2 += h1 * w[6];  a3 += h1 * w[7];
        a0 += h2 * w[8];  a1 += h2 * w[9];  a2 += h2 * w[10]; a3 += h2 * w[11];
        a0 += h3 * w[12]; a1 += h3 * w[13]; a2 += h3 * w[14]; a3 += h3 * w[15];
    }

    // 5) GELU + store (full-line writes)
    float* hp = h + ((size_t)b*NS + s)*NC;
    f16v g;
    #pragma unroll
    for (int j = 0; j < 16; ++j) g[j] = gelu_exact(a0[j]);
    ((f16v*)hp)[0] = g;
    #pragma unroll
    for (int j = 0; j < 16; ++j) g[j] = gelu_exact(a1[j]);
    ((f16v*)hp)[1] = g;
    #pragma unroll
    for (int j = 0; j < 16; ++j) g[j] = gelu_exact(a2[j]);
    ((f16v*)hp)[2] = g;
    #pragma unroll
    for (int j = 0; j < 16; ++j) g[j] = gelu_exact(a3[j]);
    ((f16v*)hp)[3] = g;
}

// Fused decoder with the same LDS staging.
__global__ void __launch_bounds__(256) k_dec(const float* __restrict__ h,
                                             const float* __restrict__ d1t,
                                             const float* __restrict__ d1b,
                                             const float* __restrict__ d2w,
                                             const float* __restrict__ d2b,
                                             float* __restrict__ out) {
    __shared__ float hs[256 * PAD];
    int t = threadIdx.x;
    int p0 = blockIdx.x * 256;
    const float4* hblk = (const float4*)(h + (size_t)p0 * NC);
    float4 ld[16];
    #pragma unroll
    for (int j = 0; j < 16; ++j) ld[j] = hblk[t + 256*j];
    #pragma unroll
    for (int j = 0; j < 16; ++j) {
        int idx = t + 256*j;
        int ss = idx >> 4, q = idx & 15;
        float* d = &hs[ss*PAD + 4*q];
        d[0] = ld[j].x; d[1] = ld[j].y; d[2] = ld[j].z; d[3] = ld[j].w;
    }
    __syncthreads();

    f16v a0 = ((const f16v*)d1b)[0];
    f16v a1 = ((const f16v*)d1b)[1];
    f16v a2 = ((const f16v*)d1b)[2];
    f16v a3 = ((const f16v*)d1b)[3];
    const float* hrow = &hs[t * PAD];
    #pragma unroll 1
    for (int i = 0; i < NC; i += 4) {
        float h0 = hrow[i], h1 = hrow[i+1], h2 = hrow[i+2], h3 = hrow[i+3];
        const f16v* w = (const f16v*)(d1t + (size_t)i*NC);
        a0 += h0 * w[0];  a1 += h0 * w[1];  a2 += h0 * w[2];  a3 += h0 * w[3];
        a0 += h1 * w[4];  a1 += h1 * w[5];  a2 += h1 * w[6];  a3 += h1 * w[7];
        a0 += h2 * w[8];  a1 += h2 * w[9];  a2 += h2 * w[10]; a3 += h2 * w[11];
        a0 += h3 * w[12]; a1 += h3 * w[13]; a2 += h3 * w[14]; a3 += h3 * w[15];
    }
    float res = d2b[0];
    #pragma unroll
    for (int j = 0; j < 16; ++j) res = fmaf(gelu_exact(a0[j]), d2w[j],      res);
    #pragma unroll
    for (int j = 0; j < 16; ++j) res = fmaf(gelu_exact(a1[j]), d2w[16 + j], res);
    #pragma unroll
    for (int j = 0; j < 16; ++j) res = fmaf(gelu_exact(a2[j]), d2w[32 + j], res);
    #pragma unroll
    for (int j = 0; j < 16; ++j) res = fmaf(gelu_exact(a3[j]), d2w[48 + j], res);
    out[p0 + t] = res;
}

extern "C" void kernel_launch(void* const* d_in, const int* in_sizes, int n_in,
                              void* d_out, int out_size, void* d_ws, size_t ws_size,
                              hipStream_t stream) {
    const float* input = (const float*)d_in[0];
    const float* enc_w = (const float*)d_in[1];
    const float* enc_b = (const float*)d_in[2];
    const float* R_re  = (const float*)d_in[3];
    const float* R_im  = (const float*)d_in[4];
    const float* Wl_w  = (const float*)d_in[5];
    const float* Wl_b  = (const float*)d_in[6];
    const float* d1_w  = (const float*)d_in[7];
    const float* d1_b  = (const float*)d_in[8];
    const float* d2_w  = (const float*)d_in[9];
    const float* d2_b  = (const float*)d_in[10];
    float* out = (float*)d_out;

    float* ws  = (float*)d_ws;
    float* h   = ws;                               // 16.78M floats
    float* T   = h   + (size_t)NB*NS*NC;           // 262144
    float* par = T   + (size_t)NS*NM2;             // NB*NSBF*NC*NM2 = 2.10M
    float* yst = par + (size_t)NB*NSBF*NC*NM2;     // NB*NM2*NC = 65536
    float* Wt  = yst + (size_t)NB*NM2*NC;          // NL*NC*NC = 16384
    float* d1t = Wt  + (size_t)NL*NC*NC;           // NC*NC = 4096

    hipLaunchKernelGGL(k_table, dim3(NS/256), dim3(256), 0, stream, T);
    hipLaunchKernelGGL(k_prep, dim3((NL*NC*NC + NC*NC + 255)/256), dim3(256), 0,
                       stream, Wl_w, d1_w, Wt, d1t);
    hipLaunchKernelGGL(k_enc, dim3((NB*NS)/256), dim3(256), 0, stream,
                       input, enc_w, enc_b, h);
    for (int l = 0; l < NL; ++l) {
        hipLaunchKernelGGL(k_fwd, dim3(NSBF, NB), dim3(256), 0, stream, h, T, par);
        hipLaunchKernelGGL(k_mix, dim3(NB), dim3(256), 0, stream,
                           par, R_re, R_im, yst, l);
        hipLaunchKernelGGL(k_spec, dim3(NS/256, NB), dim3(256), 0, stream,
                           h, yst, Wt, Wl_b, l);
    }
    hipLaunchKernelGGL(k_dec, dim3((NB*NS)/256), dim3(256), 0, stream,
                       h, d1t, d1_b, d2_w, d2_b, out);
}

// Round 7
// 432.229 us; speedup vs baseline: 1.3729x; 1.3729x over previous
//
#include <hip/hip_runtime.h>
#include <math.h>

#define NB 32
#define NS 8192
#define NC 64
#define NM 16
#define NL 4
#define NM2 32                 // 2*M (cos,sin interleaved)
#define NSBF 32                // forward-DFT superblocks per batch
#define TPOS 64                // positions per k_spec/k_dec block
#define PAD 65                 // LDS row pad (floats)

typedef float f16v __attribute__((ext_vector_type(16)));

static __device__ __forceinline__ f16v zero16() {
    f16v v;
    #pragma unroll
    for (int j = 0; j < 16; ++j) v[j] = 0.0f;
    return v;
}

static __device__ __forceinline__ float gelu_exact(float v) {
    return 0.5f * v * (1.0f + erff(v * 0.7071067811865475f));
}

// Build trig table T[s][2m]=cos(2*pi*m*s/NS), T[s][2m+1]=sin(2*pi*m*s/NS)
__global__ void k_table(float* __restrict__ T) {
    int s = blockIdx.x * blockDim.x + threadIdx.x;
    if (s >= NS) return;
    const float w = 6.283185307179586f / (float)NS;
    float* row = T + (size_t)s * NM2;
    #pragma unroll
    for (int m = 0; m < NM; ++m) {
        int idx = (m * s) & (NS - 1);
        float a = w * (float)idx;
        float sv, cv;
        sincosf(a, &sv, &cv);
        row[2*m]   = cv;
        row[2*m+1] = sv;
    }
}

// Transpose Wl_w [L][o][i] -> Wt [L][i][o]; d1_w [o][i] -> d1t [i][o]
__global__ void k_prep(const float* __restrict__ Ww, const float* __restrict__ d1w,
                       float* __restrict__ Wt, float* __restrict__ d1t) {
    int idx = blockIdx.x * 256 + threadIdx.x;
    if (idx < NL*NC*NC) {
        int l = idx / (NC*NC), r = idx % (NC*NC);
        int i = r / NC, o = r % NC;
        Wt[idx] = Ww[(size_t)l*NC*NC + (size_t)o*NC + i];
    } else if (idx < NL*NC*NC + NC*NC) {
        int r = idx - NL*NC*NC;
        int i = r / NC, o = r % NC;
        d1t[r] = d1w[(size_t)o*NC + i];
    }
}

// h[b,s,c] = input[b,s,0]*enc_w[c] + enc_b[c]
__global__ void __launch_bounds__(256) k_enc(const float* __restrict__ x,
                                             const float* __restrict__ ew,
                                             const float* __restrict__ eb,
                                             float* __restrict__ h) {
    int p = blockIdx.x * blockDim.x + threadIdx.x;   // 0..NB*NS-1
    float xv = x[p];
    float4* out = (float4*)(h + (size_t)p * NC);
    #pragma unroll
    for (int q = 0; q < NC/4; ++q) {
        float4 w4 = ((const float4*)ew)[q];
        float4 b4 = ((const float4*)eb)[q];
        out[q] = make_float4(fmaf(xv, w4.x, b4.x), fmaf(xv, w4.y, b4.y),
                             fmaf(xv, w4.z, b4.z), fmaf(xv, w4.w, b4.w));
    }
}

// Forward partial DFT. Wave = 64 channel lanes sharing one position at a time;
// trig row is wave-uniform (s_load). Accumulators are ext_vector values.
// LDS reduce buffer padded to 33 floats/row (conflict-free writes).
__global__ void __launch_bounds__(256) k_fwd(const float* __restrict__ h,
                                             const float* __restrict__ T,
                                             float* __restrict__ partial) {
    __shared__ float red[4 * NC * 33];    // 33.8 KB
    int b = blockIdx.y, sb = blockIdx.x;
    int t = threadIdx.x;
    int w = t >> 6, lane = t & 63;        // lane = channel c
    const int PPW = NS / NSBF / 4;        // 64 positions per wave
    f16v A0 = zero16(), A1 = zero16();
    int s0 = sb * (NS / NSBF) + w * PPW;
    const float* hp = h + ((size_t)b*NS + s0)*NC + lane;
    #pragma unroll 2
    for (int it = 0; it < PPW; ++it) {
        float hv = hp[(size_t)it * NC];
        int su = __builtin_amdgcn_readfirstlane(s0 + it);
        const f16v* tr = (const f16v*)(T + (size_t)su * NM2);
        A0 += hv * tr[0];
        A1 += hv * tr[1];
    }
    float* rr = &red[(w*NC + lane) * 33];
    #pragma unroll
    for (int j = 0; j < 16; ++j) rr[j] = A0[j];
    #pragma unroll
    for (int j = 0; j < 16; ++j) rr[16 + j] = A1[j];
    __syncthreads();
    float* pout = partial + ((size_t)b*NSBF + sb) * (NC*NM2);
    #pragma unroll
    for (int e = 0; e < (NC*NM2)/256; ++e) {
        int idx = t + 256*e;              // idx = c*32 + k
        int c = idx >> 5, k = idx & 31;
        pout[idx] = red[c*33 + k] + red[(NC + c)*33 + k]
                  + red[(2*NC + c)*33 + k] + red[(3*NC + c)*33 + k];
    }
}

// Reduce partials -> x_ft, apply complex R mixing, pre-scale for inverse.
// grid (NB, 4): each block redundantly reduces xf (L2-resident) and handles
// a quarter of the (o,m) pairs -> 128 blocks instead of 32.
__global__ void __launch_bounds__(256) k_mix(const float* __restrict__ partial,
                                             const float* __restrict__ Rre,
                                             const float* __restrict__ Rim,
                                             float* __restrict__ yst, int l) {
    __shared__ float xf[NC*NM2];   // 8 KB
    int b = blockIdx.x, jg = blockIdx.y, t = threadIdx.x;
    #pragma unroll
    for (int e = 0; e < (NC*NM2)/256; ++e) {
        int idx = t + 256*e;
        float s = 0.f;
        #pragma unroll 8
        for (int sb = 0; sb < NSBF; ++sb)
            s += partial[((size_t)b*NSBF + sb)*(NC*NM2) + idx];
        xf[idx] = s;
    }
    __syncthreads();
    {
        int p = t + 256*jg;                // (o,m) pair
        int o = p >> 4, m = p & 15;
        float yre = 0.f, yim = 0.f;
        #pragma unroll 8
        for (int i = 0; i < NC; ++i) {
            float xr = xf[i*NM2 + 2*m];
            float xs = xf[i*NM2 + 2*m + 1];
            size_t ridx = (((size_t)l*NC + i)*NC + o)*NM + m;
            float rr = Rre[ridx], ri = Rim[ridx];
            yre = fmaf(xr, rr, yre); yre = fmaf(xs, ri, yre);
            yim = fmaf(xr, ri, yim); yim = fmaf(-xs, rr, yim);
        }
        float* yb = yst + (size_t)b*NM2*NC;
        if (m == 0) { yb[o] = yre * (1.0f/NS); yb[NC + o] = 0.f; }
        else {
            yb[(size_t)(2*m)*NC + o]   = yre * (2.0f/NS);
            yb[(size_t)(2*m+1)*NC + o] = -yim * (2.0f/NS);
        }
    }
}

// Fused spectral + Wl + GELU, in-place on h. Block = 64 positions x 4 waves.
// Wave w computes output channels [16w,16w+16) for all 64 positions.
// og is readfirstlane'd -> weight/ys/bias rows are wave-uniform s_loads.
// h tile staged coalesced into padded LDS; 16.6 KB -> 8 blocks/CU.
__global__ void __launch_bounds__(256) k_spec(float* __restrict__ h,
                                              const float* __restrict__ yst,
                                              const float* __restrict__ Wt,
                                              const float* __restrict__ Wb,
                                              int l) {
    __shared__ float hs[TPOS * PAD];   // 16.64 KB
    int b = blockIdx.y;
    int t = threadIdx.x;
    int og = __builtin_amdgcn_readfirstlane(t >> 6);   // wave-uniform
    int p  = t & 63;
    int s0 = blockIdx.x * TPOS;
    int s  = s0 + p;

    // 1) coalesced tile load + LDS store (4 float4 per thread)
    const float4* hblk = (const float4*)(h + ((size_t)b*NS + s0)*NC);
    float4 l0 = hblk[t];
    float4 l1 = hblk[t + 256];
    float4 l2 = hblk[t + 512];
    float4 l3 = hblk[t + 768];
    {
        int ss = t >> 4, q = t & 15;
        float* d = &hs[ss*PAD + 4*q];
        d[0] = l0.x; d[1] = l0.y; d[2] = l0.z; d[3] = l0.w;
        d = &hs[(ss+16)*PAD + 4*q];
        d[0] = l1.x; d[1] = l1.y; d[2] = l1.z; d[3] = l1.w;
        d = &hs[(ss+32)*PAD + 4*q];
        d[0] = l2.x; d[1] = l2.y; d[2] = l2.z; d[3] = l2.w;
        d = &hs[(ss+48)*PAD + 4*q];
        d[0] = l3.x; d[1] = l3.y; d[2] = l3.z; d[3] = l3.w;
    }
    __syncthreads();

    const float* Wl = Wt + (size_t)l*NC*NC + og*16;    // [i][og*16..)
    const float* bl = Wb + (size_t)l*NC + og*16;
    const float* yb = yst + (size_t)b*NM2*NC + og*16;  // [k][og*16..)

    f16v acc = *(const f16v*)bl;

    // 2) spectral: acc += sum_m cos(m th)*yc_m + sin(m th)*ys_m (in-reg trig)
    {
        acc += *(const f16v*)yb;           // m=0 cos row (sin row is zero)
        float ang = (float)s * (6.283185307179586f / (float)NS);
        float c1, s1;
        sincosf(ang, &s1, &c1);
        float cm = c1, sm = s1;
        #pragma unroll 1
        for (int m = 1; m < NM; ++m) {
            f16v yc = *(const f16v*)(yb + (size_t)(2*m)*NC);
            f16v ysv = *(const f16v*)(yb + (size_t)(2*m+1)*NC);
            acc += cm * yc;
            acc += sm * ysv;
            float cn = cm*c1 - sm*s1;
            sm = cm*s1 + sm*c1;
            cm = cn;
        }
    }

    // 3) dense: acc += sum_i h[i] * Wt[i][og*16..)
    const float* hrow = &hs[p * PAD];
    #pragma unroll 4
    for (int i = 0; i < NC; ++i) {
        float hv = hrow[i];
        f16v w = *(const f16v*)(Wl + (size_t)i*NC);
        acc += hv * w;
    }

    // 4) GELU + store (64 B per thread)
    float* hp = h + ((size_t)b*NS + s)*NC + og*16;
    f16v g;
    #pragma unroll
    for (int j = 0; j < 16; ++j) g[j] = gelu_exact(acc[j]);
    *(f16v*)hp = g;
}

// Fused decoder, same og-split tile structure + cross-wave LDS reduce.
__global__ void __launch_bounds__(256) k_dec(const float* __restrict__ h,
                                             const float* __restrict__ d1t,
                                             const float* __restrict__ d1b,
                                             const float* __restrict__ d2w,
                                             const float* __restrict__ d2b,
                                             float* __restrict__ out) {
    __shared__ float hs[TPOS * PAD];
    __shared__ float red[4 * TPOS];
    int t = threadIdx.x;
    int og = __builtin_amdgcn_readfirstlane(t >> 6);
    int p  = t & 63;
    int p0 = blockIdx.x * TPOS;

    const float4* hblk = (const float4*)(h + (size_t)p0 * NC);
    float4 l0 = hblk[t];
    float4 l1 = hblk[t + 256];
    float4 l2 = hblk[t + 512];
    float4 l3 = hblk[t + 768];
    {
        int ss = t >> 4, q = t & 15;
        float* d = &hs[ss*PAD + 4*q];
        d[0] = l0.x; d[1] = l0.y; d[2] = l0.z; d[3] = l0.w;
        d = &hs[(ss+16)*PAD + 4*q];
        d[0] = l1.x; d[1] = l1.y; d[2] = l1.z; d[3] = l1.w;
        d = &hs[(ss+32)*PAD + 4*q];
        d[0] = l2.x; d[1] = l2.y; d[2] = l2.z; d[3] = l2.w;
        d = &hs[(ss+48)*PAD + 4*q];
        d[0] = l3.x; d[1] = l3.y; d[2] = l3.z; d[3] = l3.w;
    }
    __syncthreads();

    f16v acc = *(const f16v*)(d1b + og*16);
    const float* hrow = &hs[p * PAD];
    #pragma unroll 4
    for (int i = 0; i < NC; ++i) {
        float hv = hrow[i];
        f16v w = *(const f16v*)(d1t + (size_t)i*NC + og*16);
        acc += hv * w;
    }
    float res = 0.f;
    #pragma unroll
    for (int j = 0; j < 16; ++j)
        res = fmaf(gelu_exact(acc[j]), d2w[og*16 + j], res);
    red[og*TPOS + p] = res;
    __syncthreads();
    if (t < TPOS) {
        out[p0 + t] = d2b[0] + red[t] + red[TPOS + t]
                    + red[2*TPOS + t] + red[3*TPOS + t];
    }
}

extern "C" void kernel_launch(void* const* d_in, const int* in_sizes, int n_in,
                              void* d_out, int out_size, void* d_ws, size_t ws_size,
                              hipStream_t stream) {
    const float* input = (const float*)d_in[0];
    const float* enc_w = (const float*)d_in[1];
    const float* enc_b = (const float*)d_in[2];
    const float* R_re  = (const float*)d_in[3];
    const float* R_im  = (const float*)d_in[4];
    const float* Wl_w  = (const float*)d_in[5];
    const float* Wl_b  = (const float*)d_in[6];
    const float* d1_w  = (const float*)d_in[7];
    const float* d1_b  = (const float*)d_in[8];
    const float* d2_w  = (const float*)d_in[9];
    const float* d2_b  = (const float*)d_in[10];
    float* out = (float*)d_out;

    float* ws  = (float*)d_ws;
    float* h   = ws;                               // 16.78M floats
    float* T   = h   + (size_t)NB*NS*NC;           // 262144
    float* par = T   + (size_t)NS*NM2;             // NB*NSBF*NC*NM2 = 2.10M
    float* yst = par + (size_t)NB*NSBF*NC*NM2;     // NB*NM2*NC = 65536
    float* Wt  = yst + (size_t)NB*NM2*NC;          // NL*NC*NC = 16384
    float* d1t = Wt  + (size_t)NL*NC*NC;           // NC*NC = 4096

    hipLaunchKernelGGL(k_table, dim3(NS/256), dim3(256), 0, stream, T);
    hipLaunchKernelGGL(k_prep, dim3((NL*NC*NC + NC*NC + 255)/256), dim3(256), 0,
                       stream, Wl_w, d1_w, Wt, d1t);
    hipLaunchKernelGGL(k_enc, dim3((NB*NS)/256), dim3(256), 0, stream,
                       input, enc_w, enc_b, h);
    for (int l = 0; l < NL; ++l) {
        hipLaunchKernelGGL(k_fwd, dim3(NSBF, NB), dim3(256), 0, stream, h, T, par);
        hipLaunchKernelGGL(k_mix, dim3(NB, 4), dim3(256), 0, stream,
                           par, R_re, R_im, yst, l);
        hipLaunchKernelGGL(k_spec, dim3(NS/TPOS, NB), dim3(256), 0, stream,
                           h, yst, Wt, Wl_b, l);
    }
    hipLaunchKernelGGL(k_dec, dim3((NB*NS)/TPOS), dim3(256), 0, stream,
                       h, d1t, d1_b, d2_w, d2_b, out);
}

// Round 8
// 402.715 us; speedup vs baseline: 1.4735x; 1.0733x over previous
//
#include <hip/hip_runtime.h>
#include <math.h>

#define NB 32
#define NS 8192
#define NC 64
#define NM 16
#define NL 4
#define NM2 32                 // 2*M (cos,sin interleaved)
#define NSBF 32                // forward-DFT superblocks per batch
#define TPOS 128               // positions per k_spec/k_dec block (2 per thread)
#define PAD 65                 // LDS row pad (floats)

typedef float f16v __attribute__((ext_vector_type(16)));

static __device__ __forceinline__ f16v zero16() {
    f16v v;
    #pragma unroll
    for (int j = 0; j < 16; ++j) v[j] = 0.0f;
    return v;
}

static __device__ __forceinline__ float gelu_exact(float v) {
    return 0.5f * v * (1.0f + erff(v * 0.7071067811865475f));
}

// Build trig table T[s][2m]=cos(2*pi*m*s/NS), T[s][2m+1]=sin(2*pi*m*s/NS)
__global__ void k_table(float* __restrict__ T) {
    int s = blockIdx.x * blockDim.x + threadIdx.x;
    if (s >= NS) return;
    const float w = 6.283185307179586f / (float)NS;
    float* row = T + (size_t)s * NM2;
    #pragma unroll
    for (int m = 0; m < NM; ++m) {
        int idx = (m * s) & (NS - 1);
        float a = w * (float)idx;
        float sv, cv;
        sincosf(a, &sv, &cv);
        row[2*m]   = cv;
        row[2*m+1] = sv;
    }
}

// Transpose Wl_w [L][o][i] -> Wt [L][i][o]; d1_w [o][i] -> d1t [i][o]
__global__ void k_prep(const float* __restrict__ Ww, const float* __restrict__ d1w,
                       float* __restrict__ Wt, float* __restrict__ d1t) {
    int idx = blockIdx.x * 256 + threadIdx.x;
    if (idx < NL*NC*NC) {
        int l = idx / (NC*NC), r = idx % (NC*NC);
        int i = r / NC, o = r % NC;
        Wt[idx] = Ww[(size_t)l*NC*NC + (size_t)o*NC + i];
    } else if (idx < NL*NC*NC + NC*NC) {
        int r = idx - NL*NC*NC;
        int i = r / NC, o = r % NC;
        d1t[r] = d1w[(size_t)o*NC + i];
    }
}

// h[b,s,c] = input[b,s,0]*enc_w[c] + enc_b[c]  (coalesced float4 writes)
__global__ void __launch_bounds__(256) k_enc(const float* __restrict__ x,
                                             const float* __restrict__ ew,
                                             const float* __restrict__ eb,
                                             float* __restrict__ h) {
    int t = threadIdx.x;
    int base = blockIdx.x * 64;              // 64 positions per block
    float4* hout = (float4*)(h + (size_t)base * NC);
    #pragma unroll
    for (int j = 0; j < 4; ++j) {
        int idx = t + 256*j;                 // float4 index in 64x64 tile
        int sl = idx >> 4, q = idx & 15;
        float xv = x[base + sl];
        float4 w4 = ((const float4*)ew)[q];
        float4 b4 = ((const float4*)eb)[q];
        hout[idx] = make_float4(fmaf(xv, w4.x, b4.x), fmaf(xv, w4.y, b4.y),
                                fmaf(xv, w4.z, b4.z), fmaf(xv, w4.w, b4.w));
    }
}

// Forward partial DFT. Wave = 64 channel lanes sharing one position at a time;
// trig row is wave-uniform (s_load). Accumulators are ext_vector values.
__global__ void __launch_bounds__(256) k_fwd(const float* __restrict__ h,
                                             const float* __restrict__ T,
                                             float* __restrict__ partial) {
    __shared__ float red[4 * NC * 33];    // 33.8 KB
    int b = blockIdx.y, sb = blockIdx.x;
    int t = threadIdx.x;
    int w = t >> 6, lane = t & 63;        // lane = channel c
    const int PPW = NS / NSBF / 4;        // 64 positions per wave
    f16v A0 = zero16(), A1 = zero16();
    int s0 = sb * (NS / NSBF) + w * PPW;
    const float* hp = h + ((size_t)b*NS + s0)*NC + lane;
    #pragma unroll 2
    for (int it = 0; it < PPW; ++it) {
        float hv = hp[(size_t)it * NC];
        int su = __builtin_amdgcn_readfirstlane(s0 + it);
        const f16v* tr = (const f16v*)(T + (size_t)su * NM2);
        A0 += hv * tr[0];
        A1 += hv * tr[1];
    }
    float* rr = &red[(w*NC + lane) * 33];
    #pragma unroll
    for (int j = 0; j < 16; ++j) rr[j] = A0[j];
    #pragma unroll
    for (int j = 0; j < 16; ++j) rr[16 + j] = A1[j];
    __syncthreads();
    float* pout = partial + ((size_t)b*NSBF + sb) * (NC*NM2);
    #pragma unroll
    for (int e = 0; e < (NC*NM2)/256; ++e) {
        int idx = t + 256*e;              // idx = c*32 + k
        int c = idx >> 5, k = idx & 31;
        pout[idx] = red[c*33 + k] + red[(NC + c)*33 + k]
                  + red[(2*NC + c)*33 + k] + red[(3*NC + c)*33 + k];
    }
}

// Reduce partials -> x_ft, apply complex R mixing, pre-scale for inverse.
// grid (NB, 4): each block redundantly reduces xf (L2-resident) and handles
// a quarter of the (o,m) pairs.
__global__ void __launch_bounds__(256) k_mix(const float* __restrict__ partial,
                                             const float* __restrict__ Rre,
                                             const float* __restrict__ Rim,
                                             float* __restrict__ yst, int l) {
    __shared__ float xf[NC*NM2];   // 8 KB
    int b = blockIdx.x, jg = blockIdx.y, t = threadIdx.x;
    #pragma unroll
    for (int e = 0; e < (NC*NM2)/256; ++e) {
        int idx = t + 256*e;
        float s = 0.f;
        #pragma unroll 8
        for (int sb = 0; sb < NSBF; ++sb)
            s += partial[((size_t)b*NSBF + sb)*(NC*NM2) + idx];
        xf[idx] = s;
    }
    __syncthreads();
    {
        int p = t + 256*jg;                // (o,m) pair
        int o = p >> 4, m = p & 15;
        float yre = 0.f, yim = 0.f;
        #pragma unroll 8
        for (int i = 0; i < NC; ++i) {
            float xr = xf[i*NM2 + 2*m];
            float xs = xf[i*NM2 + 2*m + 1];
            size_t ridx = (((size_t)l*NC + i)*NC + o)*NM + m;
            float rr = Rre[ridx], ri = Rim[ridx];
            yre = fmaf(xr, rr, yre); yre = fmaf(xs, ri, yre);
            yim = fmaf(xr, ri, yim); yim = fmaf(-xs, rr, yim);
        }
        float* yb = yst + (size_t)b*NM2*NC;
        if (m == 0) { yb[o] = yre * (1.0f/NS); yb[NC + o] = 0.f; }
        else {
            yb[(size_t)(2*m)*NC + o]   = yre * (2.0f/NS);
            yb[(size_t)(2*m+1)*NC + o] = -yim * (2.0f/NS);
        }
    }
}

// Fused spectral + Wl + GELU, in-place on h. Block = 128 positions x 4 waves;
// thread handles positions p and p+64 for its wave's 16 output channels ->
// every wave-uniform s_load (W row, ys rows) is shared by 2 accumulators.
// Order: issue global loads -> spectral (hides vmcnt) -> LDS write -> barrier
// -> dense from LDS.
__global__ void __launch_bounds__(256) k_spec(float* __restrict__ h,
                                              const float* __restrict__ yst,
                                              const float* __restrict__ Wt,
                                              const float* __restrict__ Wb,
                                              int l) {
    __shared__ float hs[TPOS * PAD];   // 33.28 KB
    int b = blockIdx.y;
    int t = threadIdx.x;
    int og = __builtin_amdgcn_readfirstlane(t >> 6);   // wave-uniform
    int p  = t & 63;
    int s0 = blockIdx.x * TPOS;

    // 1) issue coalesced tile loads
    const float4* hblk = (const float4*)(h + ((size_t)b*NS + s0)*NC);
    float4 ld0 = hblk[t];
    float4 ld1 = hblk[t + 256];
    float4 ld2 = hblk[t + 512];
    float4 ld3 = hblk[t + 768];
    float4 ld4 = hblk[t + 1024];
    float4 ld5 = hblk[t + 1280];
    float4 ld6 = hblk[t + 1536];
    float4 ld7 = hblk[t + 1792];

    const float* Wl = Wt + (size_t)l*NC*NC + og*16;    // [i][og*16..)
    const float* bl = Wb + (size_t)l*NC + og*16;
    const float* yb = yst + (size_t)b*NM2*NC + og*16;  // [k][og*16..)

    f16v accA = *(const f16v*)bl;
    f16v accB = accA;

    // 2) spectral (overlaps the global-load latency)
    {
        f16v y0 = *(const f16v*)yb;        // m=0 cos row (sin row is zero)
        accA += y0;
        accB += y0;
        const float w1 = 6.283185307179586f / (float)NS;
        float angA = (float)(s0 + p) * w1;
        float angB = (float)(s0 + p + 64) * w1;
        float cA1, sA1, cB1, sB1;
        sincosf(angA, &sA1, &cA1);
        sincosf(angB, &sB1, &cB1);
        float cmA = cA1, smA = sA1, cmB = cB1, smB = sB1;
        #pragma unroll 1
        for (int m = 1; m < NM; ++m) {
            f16v yc  = *(const f16v*)(yb + (size_t)(2*m)*NC);
            f16v ysv = *(const f16v*)(yb + (size_t)(2*m+1)*NC);
            accA += cmA * yc;  accA += smA * ysv;
            accB += cmB * yc;  accB += smB * ysv;
            float cnA = cmA*cA1 - smA*sA1;
            smA = cmA*sA1 + smA*cA1;  cmA = cnA;
            float cnB = cmB*cB1 - smB*sB1;
            smB = cmB*sB1 + smB*cB1;  cmB = cnB;
        }
    }

    // 3) stage tile into LDS (transpose to padded per-position rows)
    {
        int ss = t >> 4, q4 = (t & 15) * 4;
        float* d;
        d = &hs[ss*PAD + q4];        d[0]=ld0.x; d[1]=ld0.y; d[2]=ld0.z; d[3]=ld0.w;
        d = &hs[(ss+16)*PAD + q4];   d[0]=ld1.x; d[1]=ld1.y; d[2]=ld1.z; d[3]=ld1.w;
        d = &hs[(ss+32)*PAD + q4];   d[0]=ld2.x; d[1]=ld2.y; d[2]=ld2.z; d[3]=ld2.w;
        d = &hs[(ss+48)*PAD + q4];   d[0]=ld3.x; d[1]=ld3.y; d[2]=ld3.z; d[3]=ld3.w;
        d = &hs[(ss+64)*PAD + q4];   d[0]=ld4.x; d[1]=ld4.y; d[2]=ld4.z; d[3]=ld4.w;
        d = &hs[(ss+80)*PAD + q4];   d[0]=ld5.x; d[1]=ld5.y; d[2]=ld5.z; d[3]=ld5.w;
        d = &hs[(ss+96)*PAD + q4];   d[0]=ld6.x; d[1]=ld6.y; d[2]=ld6.z; d[3]=ld6.w;
        d = &hs[(ss+112)*PAD + q4];  d[0]=ld7.x; d[1]=ld7.y; d[2]=ld7.z; d[3]=ld7.w;
    }
    __syncthreads();

    // 4) dense: acc{A,B} += h[p{,+64}][i] * Wt[i][og*16..)  -- shared W loads
    const float* hA = &hs[p * PAD];
    const float* hB = &hs[(p + 64) * PAD];
    #pragma unroll 8
    for (int i = 0; i < NC; ++i) {
        float va = hA[i], vb = hB[i];
        f16v w = *(const f16v*)(Wl + (size_t)i*NC);
        accA += va * w;
        accB += vb * w;
    }

    // 5) GELU + store (64 B per thread per position)
    float* hpA = h + ((size_t)b*NS + s0 + p)*NC + og*16;
    float* hpB = h + ((size_t)b*NS + s0 + p + 64)*NC + og*16;
    f16v g;
    #pragma unroll
    for (int j = 0; j < 16; ++j) g[j] = gelu_exact(accA[j]);
    *(f16v*)hpA = g;
    #pragma unroll
    for (int j = 0; j < 16; ++j) g[j] = gelu_exact(accB[j]);
    *(f16v*)hpB = g;
}

// Fused decoder, same 2-position og-split structure + cross-wave LDS reduce.
__global__ void __launch_bounds__(256) k_dec(const float* __restrict__ h,
                                             const float* __restrict__ d1t,
                                             const float* __restrict__ d1b,
                                             const float* __restrict__ d2w,
                                             const float* __restrict__ d2b,
                                             float* __restrict__ out) {
    __shared__ float hs[TPOS * PAD];
    __shared__ float red[4 * TPOS];
    int t = threadIdx.x;
    int og = __builtin_amdgcn_readfirstlane(t >> 6);
    int p  = t & 63;
    int p0 = blockIdx.x * TPOS;

    const float4* hblk = (const float4*)(h + (size_t)p0 * NC);
    float4 ld0 = hblk[t];
    float4 ld1 = hblk[t + 256];
    float4 ld2 = hblk[t + 512];
    float4 ld3 = hblk[t + 768];
    float4 ld4 = hblk[t + 1024];
    float4 ld5 = hblk[t + 1280];
    float4 ld6 = hblk[t + 1536];
    float4 ld7 = hblk[t + 1792];
    {
        int ss = t >> 4, q4 = (t & 15) * 4;
        float* d;
        d = &hs[ss*PAD + q4];        d[0]=ld0.x; d[1]=ld0.y; d[2]=ld0.z; d[3]=ld0.w;
        d = &hs[(ss+16)*PAD + q4];   d[0]=ld1.x; d[1]=ld1.y; d[2]=ld1.z; d[3]=ld1.w;
        d = &hs[(ss+32)*PAD + q4];   d[0]=ld2.x; d[1]=ld2.y; d[2]=ld2.z; d[3]=ld2.w;
        d = &hs[(ss+48)*PAD + q4];   d[0]=ld3.x; d[1]=ld3.y; d[2]=ld3.z; d[3]=ld3.w;
        d = &hs[(ss+64)*PAD + q4];   d[0]=ld4.x; d[1]=ld4.y; d[2]=ld4.z; d[3]=ld4.w;
        d = &hs[(ss+80)*PAD + q4];   d[0]=ld5.x; d[1]=ld5.y; d[2]=ld5.z; d[3]=ld5.w;
        d = &hs[(ss+96)*PAD + q4];   d[0]=ld6.x; d[1]=ld6.y; d[2]=ld6.z; d[3]=ld6.w;
        d = &hs[(ss+112)*PAD + q4];  d[0]=ld7.x; d[1]=ld7.y; d[2]=ld7.z; d[3]=ld7.w;
    }
    __syncthreads();

    f16v accA = *(const f16v*)(d1b + og*16);
    f16v accB = accA;
    const float* hA = &hs[p * PAD];
    const float* hB = &hs[(p + 64) * PAD];
    #pragma unroll 8
    for (int i = 0; i < NC; ++i) {
        float va = hA[i], vb = hB[i];
        f16v w = *(const f16v*)(d1t + (size_t)i*NC + og*16);
        accA += va * w;
        accB += vb * w;
    }
    float resA = 0.f, resB = 0.f;
    #pragma unroll
    for (int j = 0; j < 16; ++j) {
        float dw = d2w[og*16 + j];
        resA = fmaf(gelu_exact(accA[j]), dw, resA);
        resB = fmaf(gelu_exact(accB[j]), dw, resB);
    }
    red[og*TPOS + p]      = resA;
    red[og*TPOS + p + 64] = resB;
    __syncthreads();
    if (t < TPOS) {
        out[p0 + t] = d2b[0] + red[t] + red[TPOS + t]
                    + red[2*TPOS + t] + red[3*TPOS + t];
    }
}

extern "C" void kernel_launch(void* const* d_in, const int* in_sizes, int n_in,
                              void* d_out, int out_size, void* d_ws, size_t ws_size,
                              hipStream_t stream) {
    const float* input = (const float*)d_in[0];
    const float* enc_w = (const float*)d_in[1];
    const float* enc_b = (const float*)d_in[2];
    const float* R_re  = (const float*)d_in[3];
    const float* R_im  = (const float*)d_in[4];
    const float* Wl_w  = (const float*)d_in[5];
    const float* Wl_b  = (const float*)d_in[6];
    const float* d1_w  = (const float*)d_in[7];
    const float* d1_b  = (const float*)d_in[8];
    const float* d2_w  = (const float*)d_in[9];
    const float* d2_b  = (const float*)d_in[10];
    float* out = (float*)d_out;

    float* ws  = (float*)d_ws;
    float* h   = ws;                               // 16.78M floats
    float* T   = h   + (size_t)NB*NS*NC;           // 262144
    float* par = T   + (size_t)NS*NM2;             // NB*NSBF*NC*NM2 = 2.10M
    float* yst = par + (size_t)NB*NSBF*NC*NM2;     // NB*NM2*NC = 65536
    float* Wt  = yst + (size_t)NB*NM2*NC;          // NL*NC*NC = 16384
    float* d1t = Wt  + (size_t)NL*NC*NC;           // NC*NC = 4096

    hipLaunchKernelGGL(k_table, dim3(NS/256), dim3(256), 0, stream, T);
    hipLaunchKernelGGL(k_prep, dim3((NL*NC*NC + NC*NC + 255)/256), dim3(256), 0,
                       stream, Wl_w, d1_w, Wt, d1t);
    hipLaunchKernelGGL(k_enc, dim3((NB*NS)/64), dim3(256), 0, stream,
                       input, enc_w, enc_b, h);
    for (int l = 0; l < NL; ++l) {
        hipLaunchKernelGGL(k_fwd, dim3(NSBF, NB), dim3(256), 0, stream, h, T, par);
        hipLaunchKernelGGL(k_mix, dim3(NB, 4), dim3(256), 0, stream,
                           par, R_re, R_im, yst, l);
        hipLaunchKernelGGL(k_spec, dim3(NS/TPOS, NB), dim3(256), 0, stream,
                           h, yst, Wt, Wl_b, l);
    }
    hipLaunchKernelGGL(k_dec, dim3((NB*NS)/TPOS), dim3(256), 0, stream,
                       h, d1t, d1_b, d2_w, d2_b, out);
}

// Round 9
// 363.274 us; speedup vs baseline: 1.6335x; 1.1086x over previous
//
#include <hip/hip_runtime.h>
#include <math.h>

#define NB 32
#define NS 8192
#define NC 64
#define NM 16
#define NL 4
#define NM2 32                 // 2*M (cos,sin interleaved)
#define TPOS 128               // positions per tile (2 per thread)
#define NT (NS/TPOS)           // 64 tiles per batch
#define PAD 65                 // LDS row pad (floats)

typedef float f16v __attribute__((ext_vector_type(16)));
typedef float f8v  __attribute__((ext_vector_type(8)));

static __device__ __forceinline__ f8v zero8() {
    f8v v;
    #pragma unroll
    for (int j = 0; j < 8; ++j) v[j] = 0.0f;
    return v;
}

static __device__ __forceinline__ float gelu_exact(float v) {
    return 0.5f * v * (1.0f + erff(v * 0.7071067811865475f));
}

// Build trig table T[s][2m]=cos(2*pi*m*s/NS), T[s][2m+1]=sin(2*pi*m*s/NS)
__global__ void k_table(float* __restrict__ T) {
    int s = blockIdx.x * blockDim.x + threadIdx.x;
    if (s >= NS) return;
    const float w = 6.283185307179586f / (float)NS;
    float* row = T + (size_t)s * NM2;
    #pragma unroll
    for (int m = 0; m < NM; ++m) {
        int idx = (m * s) & (NS - 1);
        float a = w * (float)idx;
        float sv, cv;
        sincosf(a, &sv, &cv);
        row[2*m]   = cv;
        row[2*m+1] = sv;
    }
}

// Transpose Wl_w [L][o][i] -> Wt [L][i][o]; d1_w [o][i] -> d1t [i][o]
__global__ void k_prep(const float* __restrict__ Ww, const float* __restrict__ d1w,
                       float* __restrict__ Wt, float* __restrict__ d1t) {
    int idx = blockIdx.x * 256 + threadIdx.x;
    if (idx < NL*NC*NC) {
        int l = idx / (NC*NC), r = idx % (NC*NC);
        int i = r / NC, o = r % NC;
        Wt[idx] = Ww[(size_t)l*NC*NC + (size_t)o*NC + i];
    } else if (idx < NL*NC*NC + NC*NC) {
        int r = idx - NL*NC*NC;
        int i = r / NC, o = r % NC;
        d1t[r] = d1w[(size_t)o*NC + i];
    }
}

// Shared DFT phase: hs holds the tile's h values (rows = local position,
// PAD-strided); computes partial[c][k] = sum_s h[s,c]*T[s0+s][k] for the
// wave's 8 modes and writes to the tile's partial slot.
static __device__ __forceinline__ void dft_phase(
        const float* __restrict__ hs, const float* __restrict__ T,
        float* __restrict__ partial, int b, int tile, int s0,
        int og, int t) {
    int c = t & 63;
    f8v acc = zero8();
    const float* trow = T + (size_t)s0 * NM2 + og * 8;
    #pragma unroll 4
    for (int ss = 0; ss < TPOS; ++ss) {
        float hv = hs[ss * PAD + c];
        f8v tv = *(const f8v*)(trow + (size_t)ss * NM2);
        acc += hv * tv;
    }
    float* pout = partial + (((size_t)b*NT + tile)*NC + c)*NM2 + og*8;
    *(f8v*)pout = acc;
}

// Encoder fused with layer-0 forward DFT. Block = one 128-position tile.
__global__ void __launch_bounds__(256) k_enc(const float* __restrict__ x,
                                             const float* __restrict__ ew,
                                             const float* __restrict__ eb,
                                             const float* __restrict__ T,
                                             float* __restrict__ h,
                                             float* __restrict__ partial) {
    __shared__ float hs[TPOS * PAD];   // 33.28 KB
    int tile = blockIdx.x, b = blockIdx.y;
    int t = threadIdx.x;
    int og = __builtin_amdgcn_readfirstlane(t >> 6);
    int p  = t & 63;
    int s0 = tile * TPOS;

    float xA = x[(size_t)b*NS + s0 + p];
    float xB = x[(size_t)b*NS + s0 + p + 64];
    f16v ew16 = *(const f16v*)(ew + og*16);
    f16v eb16 = *(const f16v*)(eb + og*16);
    f16v hA = xA * ew16 + eb16;
    f16v hB = xB * ew16 + eb16;

    // global write (64B per thread per position)
    *(f16v*)(h + ((size_t)b*NS + s0 + p)*NC + og*16)      = hA;
    *(f16v*)(h + ((size_t)b*NS + s0 + p + 64)*NC + og*16) = hB;

    // LDS write (scalar, 2-way bank alias = free)
    #pragma unroll
    for (int j = 0; j < 16; ++j) hs[p*PAD + og*16 + j] = hA[j];
    #pragma unroll
    for (int j = 0; j < 16; ++j) hs[(p+64)*PAD + og*16 + j] = hB[j];
    __syncthreads();

    dft_phase(hs, T, partial, b, tile, s0, og, t);
}

// Reduce tile partials -> xf columns (this block's 8 k's), apply complex R
// mixing, pre-scale for inverse. grid (NB, 4): block jg handles m in
// [4jg, 4jg+4) i.e. k in [8jg, 8jg+8) -> reads only its quarter of partial.
__global__ void __launch_bounds__(256) k_mix(const float* __restrict__ partial,
                                             const float* __restrict__ Rre,
                                             const float* __restrict__ Rim,
                                             float* __restrict__ yst, int l) {
    __shared__ float xf[NC * 8];   // 2 KB: [c][kk], k = 8*jg + kk
    int b = blockIdx.x, jg = blockIdx.y, t = threadIdx.x;
    #pragma unroll
    for (int e = 0; e < 2; ++e) {
        int idx = t + 256*e;               // 0..511 = c*8 + kk
        int c = idx >> 3, kk = idx & 7;
        const float* pp = partial + (size_t)b*NT*NC*NM2 + (size_t)c*NM2 + 8*jg + kk;
        float s = 0.f;
        #pragma unroll 8
        for (int tile = 0; tile < NT; ++tile)
            s += pp[(size_t)tile * NC * NM2];
        xf[idx] = s;
    }
    __syncthreads();
    {
        int o = t >> 2, mq = t & 3;
        int m = 4*jg + mq;
        float yre = 0.f, yim = 0.f;
        #pragma unroll 8
        for (int i = 0; i < NC; ++i) {
            float xr = xf[i*8 + 2*mq];
            float xs = xf[i*8 + 2*mq + 1];
            size_t ridx = (((size_t)l*NC + i)*NC + o)*NM + m;
            float rr = Rre[ridx], ri = Rim[ridx];
            yre = fmaf(xr, rr, yre); yre = fmaf(xs, ri, yre);
            yim = fmaf(xr, ri, yim); yim = fmaf(-xs, rr, yim);
        }
        float* yb = yst + (size_t)b*NM2*NC;
        if (m == 0) { yb[o] = yre * (1.0f/NS); yb[NC + o] = 0.f; }
        else {
            yb[(size_t)(2*m)*NC + o]   = yre * (2.0f/NS);
            yb[(size_t)(2*m+1)*NC + o] = -yim * (2.0f/NS);
        }
    }
}

// Fused spectral + Wl + GELU (+ next-layer DFT, or decoder when LAST).
// Block = 128 positions x 4 waves; thread owns positions p,p+64 for its
// wave's 16 output channels. Phases:
//   A issue global loads  B spectral (in-reg trig)  C stage old h to LDS
//   D dense from LDS      E gelu (+global h write if !LAST)
//   F overwrite LDS with g  G DFT partial (!LAST) | decoder -> out (LAST)
template<bool LAST>
__global__ void __launch_bounds__(256) k_spec(float* __restrict__ h,
                                              const float* __restrict__ T,
                                              const float* __restrict__ yst,
                                              const float* __restrict__ Wt,
                                              const float* __restrict__ Wb,
                                              const float* __restrict__ d1t,
                                              const float* __restrict__ d1b,
                                              const float* __restrict__ d2w,
                                              const float* __restrict__ d2b,
                                              float* __restrict__ partial,
                                              float* __restrict__ outp,
                                              int l) {
    __shared__ float hs[TPOS * PAD];   // 33.28 KB
    __shared__ float red[4 * TPOS];    // 2 KB (LAST only)
    int tile = blockIdx.x, b = blockIdx.y;
    int t = threadIdx.x;
    int og = __builtin_amdgcn_readfirstlane(t >> 6);
    int p  = t & 63;
    int s0 = tile * TPOS;

    // A: issue coalesced tile loads
    const float4* hblk = (const float4*)(h + ((size_t)b*NS + s0)*NC);
    float4 ld0 = hblk[t];
    float4 ld1 = hblk[t + 256];
    float4 ld2 = hblk[t + 512];
    float4 ld3 = hblk[t + 768];
    float4 ld4 = hblk[t + 1024];
    float4 ld5 = hblk[t + 1280];
    float4 ld6 = hblk[t + 1536];
    float4 ld7 = hblk[t + 1792];

    const float* Wl = Wt + (size_t)l*NC*NC + og*16;    // [i][og*16..)
    const float* bl = Wb + (size_t)l*NC + og*16;
    const float* yb = yst + (size_t)b*NM2*NC + og*16;  // [k][og*16..)

    f16v accA = *(const f16v*)bl;
    f16v accB = accA;

    // B: spectral (overlaps global-load latency)
    {
        f16v y0 = *(const f16v*)yb;        // m=0 cos row (sin row is zero)
        accA += y0;
        accB += y0;
        const float w1 = 6.283185307179586f / (float)NS;
        float angA = (float)(s0 + p) * w1;
        float angB = (float)(s0 + p + 64) * w1;
        float cA1, sA1, cB1, sB1;
        sincosf(angA, &sA1, &cA1);
        sincosf(angB, &sB1, &cB1);
        float cmA = cA1, smA = sA1, cmB = cB1, smB = sB1;
        #pragma unroll 1
        for (int m = 1; m < NM; ++m) {
            f16v yc  = *(const f16v*)(yb + (size_t)(2*m)*NC);
            f16v ysv = *(const f16v*)(yb + (size_t)(2*m+1)*NC);
            accA += cmA * yc;  accA += smA * ysv;
            accB += cmB * yc;  accB += smB * ysv;
            float cnA = cmA*cA1 - smA*sA1;
            smA = cmA*sA1 + smA*cA1;  cmA = cnA;
            float cnB = cmB*cB1 - smB*sB1;
            smB = cmB*sB1 + smB*cB1;  cmB = cnB;
        }
    }

    // C: stage old h into LDS (padded per-position rows)
    {
        int ss = t >> 4, q4 = (t & 15) * 4;
        float* d;
        d = &hs[ss*PAD + q4];        d[0]=ld0.x; d[1]=ld0.y; d[2]=ld0.z; d[3]=ld0.w;
        d = &hs[(ss+16)*PAD + q4];   d[0]=ld1.x; d[1]=ld1.y; d[2]=ld1.z; d[3]=ld1.w;
        d = &hs[(ss+32)*PAD + q4];   d[0]=ld2.x; d[1]=ld2.y; d[2]=ld2.z; d[3]=ld2.w;
        d = &hs[(ss+48)*PAD + q4];   d[0]=ld3.x; d[1]=ld3.y; d[2]=ld3.z; d[3]=ld3.w;
        d = &hs[(ss+64)*PAD + q4];   d[0]=ld4.x; d[1]=ld4.y; d[2]=ld4.z; d[3]=ld4.w;
        d = &hs[(ss+80)*PAD + q4];   d[0]=ld5.x; d[1]=ld5.y; d[2]=ld5.z; d[3]=ld5.w;
        d = &hs[(ss+96)*PAD + q4];   d[0]=ld6.x; d[1]=ld6.y; d[2]=ld6.z; d[3]=ld6.w;
        d = &hs[(ss+112)*PAD + q4];  d[0]=ld7.x; d[1]=ld7.y; d[2]=ld7.z; d[3]=ld7.w;
    }
    __syncthreads();

    // D: dense from LDS, W rows shared by both accumulators
    const float* hA = &hs[p * PAD];
    const float* hB = &hs[(p + 64) * PAD];
    #pragma unroll 8
    for (int i = 0; i < NC; ++i) {
        float va = hA[i], vb = hB[i];
        f16v w = *(const f16v*)(Wl + (size_t)i*NC);
        accA += va * w;
        accB += vb * w;
    }

    // E: gelu (+ global h write unless LAST)
    f16v gA, gB;
    #pragma unroll
    for (int j = 0; j < 16; ++j) gA[j] = gelu_exact(accA[j]);
    #pragma unroll
    for (int j = 0; j < 16; ++j) gB[j] = gelu_exact(accB[j]);
    if (!LAST) {
        *(f16v*)(h + ((size_t)b*NS + s0 + p)*NC + og*16)      = gA;
        *(f16v*)(h + ((size_t)b*NS + s0 + p + 64)*NC + og*16) = gB;
    }

    // F: overwrite LDS with g (all dense reads complete first)
    __syncthreads();
    #pragma unroll
    for (int j = 0; j < 16; ++j) hs[p*PAD + og*16 + j] = gA[j];
    #pragma unroll
    for (int j = 0; j < 16; ++j) hs[(p+64)*PAD + og*16 + j] = gB[j];
    __syncthreads();

    if (!LAST) {
        // G: forward DFT of the new h tile for the next layer
        dft_phase(hs, T, partial, b, tile, s0, og, t);
    } else {
        // G': decoder from LDS -> out
        f16v aA = *(const f16v*)(d1b + og*16);
        f16v aB = aA;
        #pragma unroll 8
        for (int i = 0; i < NC; ++i) {
            float va = hA[i], vb = hB[i];
            f16v w = *(const f16v*)(d1t + (size_t)i*NC + og*16);
            aA += va * w;
            aB += vb * w;
        }
        float resA = 0.f, resB = 0.f;
        #pragma unroll
        for (int j = 0; j < 16; ++j) {
            float dw = d2w[og*16 + j];
            resA = fmaf(gelu_exact(aA[j]), dw, resA);
            resB = fmaf(gelu_exact(aB[j]), dw, resB);
        }
        red[og*TPOS + p]      = resA;
        red[og*TPOS + p + 64] = resB;
        __syncthreads();
        if (t < TPOS) {
            outp[(size_t)b*NS + s0 + t] = d2b[0] + red[t] + red[TPOS + t]
                                        + red[2*TPOS + t] + red[3*TPOS + t];
        }
    }
}

extern "C" void kernel_launch(void* const* d_in, const int* in_sizes, int n_in,
                              void* d_out, int out_size, void* d_ws, size_t ws_size,
                              hipStream_t stream) {
    const float* input = (const float*)d_in[0];
    const float* enc_w = (const float*)d_in[1];
    const float* enc_b = (const float*)d_in[2];
    const float* R_re  = (const float*)d_in[3];
    const float* R_im  = (const float*)d_in[4];
    const float* Wl_w  = (const float*)d_in[5];
    const float* Wl_b  = (const float*)d_in[6];
    const float* d1_w  = (const float*)d_in[7];
    const float* d1_b  = (const float*)d_in[8];
    const float* d2_w  = (const float*)d_in[9];
    const float* d2_b  = (const float*)d_in[10];
    float* out = (float*)d_out;

    float* ws  = (float*)d_ws;
    float* h   = ws;                               // NB*NS*NC = 16.78M floats
    float* T   = h   + (size_t)NB*NS*NC;           // NS*NM2 = 262144
    float* par = T   + (size_t)NS*NM2;             // NB*NT*NC*NM2 = 4.19M
    float* yst = par + (size_t)NB*NT*NC*NM2;       // NB*NM2*NC = 65536
    float* Wt  = yst + (size_t)NB*NM2*NC;          // NL*NC*NC = 16384
    float* d1t = Wt  + (size_t)NL*NC*NC;           // NC*NC = 4096

    hipLaunchKernelGGL(k_table, dim3(NS/256), dim3(256), 0, stream, T);
    hipLaunchKernelGGL(k_prep, dim3((NL*NC*NC + NC*NC + 255)/256), dim3(256), 0,
                       stream, Wl_w, d1_w, Wt, d1t);
    hipLaunchKernelGGL(k_enc, dim3(NT, NB), dim3(256), 0, stream,
                       input, enc_w, enc_b, T, h, par);
    for (int l = 0; l < NL; ++l) {
        hipLaunchKernelGGL(k_mix, dim3(NB, 4), dim3(256), 0, stream,
                           par, R_re, R_im, yst, l);
        if (l < NL - 1) {
            hipLaunchKernelGGL((k_spec<false>), dim3(NT, NB), dim3(256), 0, stream,
                               h, T, yst, Wt, Wl_b, d1t, d1_b, d2_w, d2_b,
                               par, out, l);
        } else {
            hipLaunchKernelGGL((k_spec<true>), dim3(NT, NB), dim3(256), 0, stream,
                               h, T, yst, Wt, Wl_b, d1t, d1_b, d2_w, d2_b,
                               par, out, l);
        }
    }
}